// Round 1
// baseline (382.584 us; speedup 1.0000x reference)
//
#include <hip/hip_runtime.h>
#include <hip/hip_bf16.h>
#include <stdint.h>

// Sizes fixed by the problem
#define B_N 4096
#define P_N 32
#define C_N 512
#define LABC 0.1f       // 2/(ALPHA*NORM)
#define N_II 528        // 33*32/2 upper-triangle 128x128 tiles of the 4096x4096 Gram
// Interleave ii blocks 1-in-9 through the grid so the compute-bound ii tiles
// overlap the memory-bound pf stream instead of running first in a burst.
#define GRID_TOTAL (N_II * 9)   // 4752
#define N_TT (GRID_TOTAL - N_II) // 4224 tt slots (4096 real + 128 early-exit)

typedef float  floatx4 __attribute__((ext_vector_type(4)));
typedef __bf16 bf16x8  __attribute__((ext_vector_type(8)));

__device__ __forceinline__ unsigned short f2bf(float x) {
    return __builtin_bit_cast(unsigned short, __float2bfloat16(x));
}
__device__ __forceinline__ uint4 pack8(const float4& v0, const float4& v1) {
    uint4 pk;
    pk.x = (unsigned)f2bf(v0.x) | ((unsigned)f2bf(v0.y) << 16);
    pk.y = (unsigned)f2bf(v0.z) | ((unsigned)f2bf(v0.w) << 16);
    pk.z = (unsigned)f2bf(v1.x) | ((unsigned)f2bf(v1.y) << 16);
    pk.w = (unsigned)f2bf(v1.z) | ((unsigned)f2bf(v1.w) << 16);
    return pk;
}
__device__ __forceinline__ void bfly_reduce2(float& a, float& b) {
#pragma unroll
    for (int m = 1; m < 64; m <<= 1) {
        a += __shfl_xor(a, m, 64);
        b += __shfl_xor(b, m, 64);
    }
}
__device__ __forceinline__ void bfly_reduce1(float& a) {
#pragma unroll
    for (int m = 1; m < 64; m <<= 1) a += __shfl_xor(a, m, 64);
}

// ---------------- kernel A: normalize feats -> bf16, mae partials ----------------
__global__ __launch_bounds__(256) void k_prep(const float* __restrict__ feats,
                                              const float* __restrict__ pred,
                                              const float* __restrict__ targ,
                                              unsigned short* __restrict__ fb,
                                              float* __restrict__ maePart) {
    const int wave = threadIdx.x >> 6, lane = threadIdx.x & 63;
    const int row = blockIdx.x * 4 + wave;
    const float* src = feats + (size_t)row * C_N + lane * 8;
    float4 v0 = *(const float4*)src;
    float4 v1 = *(const float4*)(src + 4);
    float ss = v0.x*v0.x + v0.y*v0.y + v0.z*v0.z + v0.w*v0.w
             + v1.x*v1.x + v1.y*v1.y + v1.z*v1.z + v1.w*v1.w;
    bfly_reduce1(ss);
    const float inv = rsqrtf(fmaxf(ss, 1e-24f));
    float4 n0 = {v0.x*inv, v0.y*inv, v0.z*inv, v0.w*inv};
    float4 n1 = {v1.x*inv, v1.y*inv, v1.z*inv, v1.w*inv};
    *(uint4*)(fb + (size_t)row * C_N + lane * 8) = pack8(n0, n1);

    if (wave == 0) {  // mae partials for this block's 4 rows
        float v = 0.f;
        if (lane < 4) {
            const int r = blockIdx.x * 4 + lane;
            v = fabsf(pred[r] - targ[r]);
        }
        v += __shfl_xor(v, 1, 64);
        v += __shfl_xor(v, 2, 64);
        if (lane == 0) maePart[blockIdx.x] = v;
    }
}

// ---------------- kernel B: fused ii + tt/it, interleaved 1-in-9 ----------------
#define APAD 130
struct TTsm {
    unsigned short pfs[64 * 33 * 8];  // [chunk 0..63][row 0..32][8 bf16]; row 32 = f_norm
    float psS[P_N];
    float rdiag[P_N];
    float redT[4], redI[4];
};
struct IIsm {
    unsigned short As[4 * APAD * 8];
    unsigned short Bs[4 * APAD * 8];
    float tm[128], tn[128];
    float red[4];
};
union SMu { TTsm tt; IIsm ii; };

__global__ __launch_bounds__(256) void k_fused(const float* __restrict__ pf_g,
                                               const float* __restrict__ ps_g,
                                               const float* __restrict__ targets,
                                               const unsigned short* __restrict__ fb,
                                               double* __restrict__ partII,
                                               double* __restrict__ partTT,
                                               double* __restrict__ partIT) {
    __shared__ __align__(16) SMu sm;
    const int tid = threadIdx.x, wave = tid >> 6, lane = tid & 63;
    const int quad = lane >> 4, l15 = lane & 15;
    const int bid = blockIdx.x;
    const bool isII = (bid % 9) == 0;

    if (isII) {
        // ================= image-image: 128x128 upper-triangle Gram tile =================
        IIsm& S = sm.ii;
        int bm = 0, rem = bid / 9;
        while (rem >= 32 - bm) { rem -= 32 - bm; ++bm; }
        const int bn = bm + rem;
        const int wr = wave >> 1, wc = wave & 1;
        const int mbase = bm * 128, nbase = bn * 128;

        if (tid < 128) S.tm[tid] = targets[mbase + tid];
        else           S.tn[tid - 128] = targets[nbase + tid - 128];

        const int row = tid >> 1, half = tid & 1;
        const unsigned short* aSrc = fb + (size_t)(mbase + row) * C_N + half * 16;
        const unsigned short* bSrc = fb + (size_t)(nbase + row) * C_N + half * 16;
        const int c0 = half * 2, c1 = half * 2 + 1;

        floatx4 accv[16];
#pragma unroll
        for (int i = 0; i < 16; ++i) accv[i] = (floatx4){0.f, 0.f, 0.f, 0.f};

        uint4 a0 = *(const uint4*)(aSrc);
        uint4 a1 = *(const uint4*)(aSrc + 8);
        uint4 b0 = *(const uint4*)(bSrc);
        uint4 b1 = *(const uint4*)(bSrc + 8);

        for (int ks = 0; ks < 16; ++ks) {
            __syncthreads();
            *(uint4*)&S.As[((size_t)c0 * APAD + row) * 8] = a0;
            *(uint4*)&S.As[((size_t)c1 * APAD + row) * 8] = a1;
            *(uint4*)&S.Bs[((size_t)c0 * APAD + row) * 8] = b0;
            *(uint4*)&S.Bs[((size_t)c1 * APAD + row) * 8] = b1;
            __syncthreads();
            if (ks < 15) {
                const int off = (ks + 1) * 32;
                a0 = *(const uint4*)(aSrc + off);
                a1 = *(const uint4*)(aSrc + off + 8);
                b0 = *(const uint4*)(bSrc + off);
                b1 = *(const uint4*)(bSrc + off + 8);
            }
            bf16x8 af[4], bfv[4];
#pragma unroll
            for (int t = 0; t < 4; ++t)
                af[t] = __builtin_bit_cast(bf16x8, *(const uint4*)&S.As[((size_t)quad * APAD + wr * 64 + t * 16 + l15) * 8]);
#pragma unroll
            for (int t = 0; t < 4; ++t)
                bfv[t] = __builtin_bit_cast(bf16x8, *(const uint4*)&S.Bs[((size_t)quad * APAD + wc * 64 + t * 16 + l15) * 8]);
#pragma unroll
            for (int ti = 0; ti < 4; ++ti)
#pragma unroll
                for (int tj = 0; tj < 4; ++tj)
                    accv[ti * 4 + tj] = __builtin_amdgcn_mfma_f32_16x16x32_bf16(af[ti], bfv[tj], accv[ti * 4 + tj], 0, 0, 0);
        }

        float s = 0.f;
#pragma unroll
        for (int ti = 0; ti < 4; ++ti)
#pragma unroll
            for (int tj = 0; tj < 4; ++tj)
#pragma unroll
                for (int r = 0; r < 4; ++r) {
                    const int p = wr * 64 + ti * 16 + quad * 4 + r;
                    const int q = wc * 64 + tj * 16 + l15;
                    const float lab = 1.f - LABC * fabsf(S.tm[p] - S.tn[q]);
                    s += fabsf(accv[ti * 4 + tj][r] - lab);
                }
        if (bm != bn) s *= 2.f;
        bfly_reduce1(s);
        if (lane == 0) S.red[wave] = s;
        __syncthreads();
        if (tid == 0) partII[bid / 9] = (double)(S.red[0] + S.red[1] + S.red[2] + S.red[3]);
    } else {
        // ================= text-text + image-text for one b =================
        const int b = bid - (bid / 9) - 1;   // dense 0..4223 over tt slots
        TTsm& S = sm.tt;
        if (b >= B_N) {
            if (tid == 0) { partTT[b] = 0.0; partIT[b] = 0.0; }
            return;
        }

        // Stage ALL global loads into registers first: 16 outstanding 16B loads
        // per thread keeps ~4 KB/SIMD in flight -> covers HBM latency at full BW.
        const float* base = pf_g + (size_t)b * P_N * C_N;
        uint4 st[16];
#pragma unroll
        for (int i = 0; i < 8; ++i) {
            const float* src = base + (wave * 8 + i) * C_N + lane * 8;
            st[2 * i]     = *(const uint4*)src;
            st[2 * i + 1] = *(const uint4*)(src + 4);
        }
        uint4 fReg = {0u, 0u, 0u, 0u};
        if (wave == 0) fReg = *(const uint4*)(fb + (size_t)b * C_N + lane * 8);
        if (tid < P_N) S.psS[tid] = ps_g[b * P_N + tid];
        const float tb = targets[b];

#pragma unroll
        for (int i = 0; i < 8; ++i) {
            const int r = wave * 8 + i;
            const float4 v0 = __builtin_bit_cast(float4, st[2 * i]);
            const float4 v1 = __builtin_bit_cast(float4, st[2 * i + 1]);
            *(uint4*)&S.pfs[((size_t)lane * 33 + r) * 8] = pack8(v0, v1);
        }
        if (wave == 0) *(uint4*)&S.pfs[((size_t)lane * 33 + 32) * 8] = fReg;
        __syncthreads();

        // Gram of raw-bf16 pf (4 tiles, one per wave) + f-row tiles on waves 0,1
        const int pt = (wave >> 1) * 16, qt = (wave & 1) * 16;
        const bool doF = (wave < 2);  // f-tile cols == qt for waves 0,1
        floatx4 acc4 = {0.f, 0.f, 0.f, 0.f};
        floatx4 accF = {0.f, 0.f, 0.f, 0.f};
        const uint4 zero4 = {0u, 0u, 0u, 0u};
#pragma unroll
        for (int kk = 0; kk < 16; ++kk) {
            const int ch = kk * 4 + quad;
            bf16x8 a = __builtin_bit_cast(bf16x8, *(const uint4*)&S.pfs[((size_t)ch * 33 + pt + l15) * 8]);
            bf16x8 bb = __builtin_bit_cast(bf16x8, *(const uint4*)&S.pfs[((size_t)ch * 33 + qt + l15) * 8]);
            acc4 = __builtin_amdgcn_mfma_f32_16x16x32_bf16(a, bb, acc4, 0, 0, 0);
            if (doF) {
                uint4 fr = *(const uint4*)&S.pfs[((size_t)ch * 33 + 32) * 8];  // broadcast read
                bf16x8 af = __builtin_bit_cast(bf16x8, (l15 == 0) ? fr : zero4);
                accF = __builtin_amdgcn_mfma_f32_16x16x32_bf16(af, bb, accF, 0, 0, 0);
            }
        }
        // diagonal -> rsqrt (tiles (0,0) wave0 and (16,16) wave3)
        if (pt == qt) {
            if ((l15 >> 2) == quad) S.rdiag[pt + l15] = rsqrtf(fmaxf(acc4[l15 & 3], 1e-24f));
        }
        __syncthreads();

        float tt_sum = 0.f, it_sum = 0.f;
#pragma unroll
        for (int r = 0; r < 4; ++r) {
            const int p = pt + quad * 4 + r;
            const int q = qt + l15;
            const float val = acc4[r] * S.rdiag[p] * S.rdiag[q];
            const float lab = 1.f - LABC * fabsf(S.psS[p] - S.psS[q]);
            tt_sum += fabsf(val - lab);
        }
        if (doF && quad == 0) {  // D row 0 of the f-tile: lanes quad==0, reg 0
            const int q = qt + l15;
            const float val = accF[0] * S.rdiag[q];
            const float lab = 1.f - LABC * fabsf(tb - S.psS[q]);
            it_sum = fabsf(val - lab);
        }
        bfly_reduce2(tt_sum, it_sum);
        if (lane == 0) { S.redT[wave] = tt_sum; S.redI[wave] = it_sum; }
        __syncthreads();
        if (tid == 0) {
            partTT[b] = (double)(S.redT[0] + S.redT[1] + S.redT[2] + S.redT[3]);
            partIT[b] = (double)(S.redI[0] + S.redI[1] + S.redI[2] + S.redI[3]);
        }
    }
}

// ---------------- kernel C: finalize (reduce partials, no atomics anywhere) ----------------
__global__ __launch_bounds__(256) void k_final(const double* __restrict__ partII,
                                               const double* __restrict__ partTT,
                                               const double* __restrict__ partIT,
                                               const float* __restrict__ maePart,
                                               float* __restrict__ out) {
    __shared__ double redA[4], redB[4], redC[4];
    __shared__ float redM[4];
    const int tid = threadIdx.x, wave = tid >> 6, lane = tid & 63;

    double sII = 0.0, sTT = 0.0, sIT = 0.0;
    for (int i = tid; i < N_II; i += 256) sII += partII[i];
    for (int i = tid; i < N_TT; i += 256) { sTT += partTT[i]; sIT += partIT[i]; }
    float sM = maePart[tid] + maePart[tid + 256] + maePart[tid + 512] + maePart[tid + 768];

#pragma unroll
    for (int m = 1; m < 64; m <<= 1) {
        sII += __shfl_xor(sII, m, 64);
        sTT += __shfl_xor(sTT, m, 64);
        sIT += __shfl_xor(sIT, m, 64);
        sM  += __shfl_xor(sM, m, 64);
    }
    if (lane == 0) { redA[wave] = sII; redB[wave] = sTT; redC[wave] = sIT; redM[wave] = sM; }
    __syncthreads();
    if (tid == 0) {
        const double ii = redA[0] + redA[1] + redA[2] + redA[3];
        const double tt = redB[0] + redB[1] + redB[2] + redB[3];
        const double it = redC[0] + redC[1] + redC[2] + redC[3];
        out[0] = (float)(ii / (double)((size_t)B_N * B_N));        // image_image
        out[1] = (float)(tt / (double)((size_t)B_N * P_N * P_N));  // text_text
        out[2] = (float)(it / (double)((size_t)B_N * P_N));        // image_text
        out[3] = (redM[0] + redM[1] + redM[2] + redM[3]) * (1.f / B_N);  // mae
    }
}

extern "C" void kernel_launch(void* const* d_in, const int* in_sizes, int n_in,
                              void* d_out, int out_size, void* d_ws, size_t ws_size,
                              hipStream_t stream) {
    const float* pred  = (const float*)d_in[0];  // (B,)
    const float* targ  = (const float*)d_in[1];  // (B,)
    const float* feats = (const float*)d_in[2];  // (B,C)
    const float* pf    = (const float*)d_in[3];  // (B,P,C)
    const float* ps    = (const float*)d_in[4];  // (B,P)
    float* out = (float*)d_out;

    float* maePart      = (float*)d_ws;                               // 4 KB (1024 floats)
    double* partII      = (double*)((char*)d_ws + 4096);              // 528 doubles
    double* partTT      = (double*)((char*)d_ws + 16384);             // 4224 doubles
    double* partIT      = (double*)((char*)d_ws + 65536);             // 4224 doubles
    unsigned short* fb  = (unsigned short*)((char*)d_ws + 131072);    // f_norm bf16: 4 MB

    k_prep<<<B_N / 4, 256, 0, stream>>>(feats, pred, targ, fb, maePart);
    k_fused<<<GRID_TOTAL, 256, 0, stream>>>(pf, ps, targ, fb, partII, partTT, partIT);
    k_final<<<1, 256, 0, stream>>>(partII, partTT, partIT, maePart, out);
}